// Round 1
// baseline (652.401 us; speedup 1.0000x reference)
//
#include <hip/hip_runtime.h>

#define FDIM 64
#define TFDIM 192  // 3*F

// ---------------- zero init for histogram/cursor ----------------
__global__ void zero_kernel(int* __restrict__ count, int* __restrict__ cursor, int n) {
    int i = blockIdx.x * blockDim.x + threadIdx.x;
    if (i < n) { count[i] = 0; cursor[i] = 0; }
}

// ---------------- per-atom MLP: t = silu(s@W1+b1)@W2 + b2 ----------------
__global__ __launch_bounds__(256) void mlp_kernel(
    const float* __restrict__ s, const float* __restrict__ W1,
    const float* __restrict__ b1, const float* __restrict__ W2,
    const float* __restrict__ b2, float* __restrict__ t, int n_atoms) {
    __shared__ float s_lds[4][FDIM];
    __shared__ float h_lds[4][FDIM];
    const int a = threadIdx.x >> 6;
    const int f = threadIdx.x & 63;
    const int atom = blockIdx.x * 4 + a;
    const bool active = atom < n_atoms;
    const int atomc = active ? atom : 0;

    s_lds[a][f] = s[(size_t)atomc * FDIM + f];
    __syncthreads();

    float acc = b1[f];
#pragma unroll
    for (int k = 0; k < FDIM; ++k)
        acc = fmaf(s_lds[a][k], W1[k * FDIM + f], acc);
    // silu
    h_lds[a][f] = acc / (1.0f + __expf(-acc));
    __syncthreads();

    float o0 = b2[f], o1 = b2[FDIM + f], o2 = b2[2 * FDIM + f];
#pragma unroll
    for (int k = 0; k < FDIM; ++k) {
        float hk = h_lds[a][k];
        o0 = fmaf(hk, W2[k * TFDIM + f], o0);
        o1 = fmaf(hk, W2[k * TFDIM + FDIM + f], o1);
        o2 = fmaf(hk, W2[k * TFDIM + 2 * FDIM + f], o2);
    }
    if (active) {
        size_t base = (size_t)atom * TFDIM;
        t[base + f] = o0;
        t[base + FDIM + f] = o1;
        t[base + 2 * FDIM + f] = o2;
    }
}

// ---------------- histogram of idx_i ----------------
__global__ void hist_kernel(const int* __restrict__ idx_i, int* __restrict__ count, int n_pairs) {
    for (int p = blockIdx.x * blockDim.x + threadIdx.x; p < n_pairs; p += gridDim.x * blockDim.x)
        atomicAdd(&count[idx_i[p]], 1);
}

// ---------------- single-block exclusive scan (n ~ 50k) ----------------
__global__ __launch_bounds__(1024) void scan_kernel(const int* __restrict__ count,
                                                    int* __restrict__ offsets, int n) {
    __shared__ int lds[1024];
    __shared__ int running_s;
    if (threadIdx.x == 0) running_s = 0;
    __syncthreads();
    for (int base = 0; base < n; base += 1024) {
        int i = base + (int)threadIdx.x;
        int val = (i < n) ? count[i] : 0;
        lds[threadIdx.x] = val;
        __syncthreads();
        for (int off = 1; off < 1024; off <<= 1) {
            int add = (threadIdx.x >= (unsigned)off) ? lds[threadIdx.x - off] : 0;
            __syncthreads();
            lds[threadIdx.x] += add;
            __syncthreads();
        }
        int incl = lds[threadIdx.x];
        int r = running_s;
        if (i < n) offsets[i] = r + incl - val;
        __syncthreads();
        if (threadIdx.x == 1023) running_s = r + lds[1023];
        __syncthreads();
    }
    if (threadIdx.x == 0) offsets[n] = running_s;
}

// ---------------- scatter pair ids into per-atom buckets ----------------
__global__ void scatter_kernel(const int* __restrict__ idx_i, const int* __restrict__ offsets,
                               int* __restrict__ cursor, int* __restrict__ sorted, int n_pairs) {
    for (int p = blockIdx.x * blockDim.x + threadIdx.x; p < n_pairs; p += gridDim.x * blockDim.x) {
        int i = idx_i[p];
        int pos = offsets[i] + atomicAdd(&cursor[i], 1);
        sorted[pos] = p;
    }
}

// ---------------- main: one block per atom i, 256 output floats ----------------
__global__ __launch_bounds__(256) void main_kernel(
    const float* __restrict__ s, const float* __restrict__ v,
    const float* __restrict__ Wij, const float* __restrict__ dir,
    const int* __restrict__ idx_j, const float* __restrict__ t,
    const int* __restrict__ offsets, const int* __restrict__ sorted,
    float* __restrict__ q_out, float* __restrict__ mu_out) {
    __shared__ int p_lds[64];
    __shared__ int j_lds[64];
    const int i = blockIdx.x;
    const int tid = threadIdx.x;
    const int f = tid & 63;
    const int part = tid >> 6;  // 0: q (ds1); 1..3: mu rows d=part-1
    const int start = offsets[i];
    const int end = offsets[i + 1];

    float acc = 0.0f;
    for (int cbase = start; cbase < end; cbase += 64) {
        int m = end - cbase;
        if (m > 64) m = 64;
        __syncthreads();
        if (part == 0 && f < m) {
            int p = sorted[cbase + f];
            p_lds[f] = p;
            j_lds[f] = idx_j[p];
        }
        __syncthreads();
        if (part == 0) {
            for (int k = 0; k < m; ++k) {
                int p = p_lds[k], j = j_lds[k];
                acc = fmaf(Wij[(size_t)p * TFDIM + f], t[(size_t)j * TFDIM + f], acc);
            }
        } else {
            const int d = part - 1;
            for (int k = 0; k < m; ++k) {
                int p = p_lds[k], j = j_lds[k];
                float w2 = Wij[(size_t)p * TFDIM + FDIM + f];
                float t2 = t[(size_t)j * TFDIM + FDIM + f];
                float w3 = Wij[(size_t)p * TFDIM + 2 * FDIM + f];
                float t3 = t[(size_t)j * TFDIM + 2 * FDIM + f];
                float vj = v[(size_t)j * TFDIM + d * FDIM + f];
                // dmu = ds2*dir + ds3*v_j
                acc = fmaf(w2 * t2, dir[(size_t)p * 3 + d], fmaf(w3 * t3, vj, acc));
            }
        }
    }

    if (part == 0) {
        q_out[(size_t)i * FDIM + f] = s[(size_t)i * FDIM + f] + acc;
    } else {
        const int d = part - 1;
        size_t o = (size_t)i * TFDIM + d * FDIM + f;
        mu_out[o] = v[o] + acc;
    }
}

extern "C" void kernel_launch(void* const* d_in, const int* in_sizes, int n_in,
                              void* d_out, int out_size, void* d_ws, size_t ws_size,
                              hipStream_t stream) {
    const float* s   = (const float*)d_in[0];   // [N,1,F]
    const float* v   = (const float*)d_in[1];   // [N,3,F]
    const float* Wij = (const float*)d_in[2];   // [P,3F]
    const float* dir = (const float*)d_in[3];   // [P,3]
    const int*   pl  = (const int*)d_in[4];     // [2,P]
    const float* W1  = (const float*)d_in[5];   // [F,F]
    const float* b1  = (const float*)d_in[6];   // [F]
    const float* W2  = (const float*)d_in[7];   // [F,3F]
    const float* b2  = (const float*)d_in[8];   // [3F]

    const int n_atoms = in_sizes[0] / FDIM;
    const int n_pairs = in_sizes[3] / 3;
    const int* idx_i = pl;
    const int* idx_j = pl + n_pairs;

    // workspace layout
    char* ws = (char*)d_ws;
    float* t = (float*)ws;                                   // n_atoms * 192 f32
    size_t t_bytes = (size_t)n_atoms * TFDIM * sizeof(float);
    int* count   = (int*)(ws + t_bytes);                     // n_atoms
    int* offsets = count + n_atoms;                          // n_atoms + 1
    int* cursor  = offsets + n_atoms + 1;                    // n_atoms
    int* sorted  = cursor + n_atoms;                         // n_pairs

    float* q_out  = (float*)d_out;                           // [N,1,F]
    float* mu_out = q_out + (size_t)n_atoms * FDIM;          // [N,3,F]

    zero_kernel<<<(n_atoms + 255) / 256, 256, 0, stream>>>(count, cursor, n_atoms);
    mlp_kernel<<<(n_atoms + 3) / 4, 256, 0, stream>>>(s, W1, b1, W2, b2, t, n_atoms);
    hist_kernel<<<2048, 256, 0, stream>>>(idx_i, count, n_pairs);
    scan_kernel<<<1, 1024, 0, stream>>>(count, offsets, n_atoms);
    scatter_kernel<<<2048, 256, 0, stream>>>(idx_i, offsets, cursor, sorted, n_pairs);
    main_kernel<<<n_atoms, 256, 0, stream>>>(s, v, Wij, dir, idx_j, t, offsets, sorted,
                                             q_out, mu_out);
}

// Round 2
// 553.310 us; speedup vs baseline: 1.1791x; 1.1791x over previous
//
#include <hip/hip_runtime.h>

#define FDIM 64
#define TFDIM 192  // 3*F
#define MLP_A 8

// ---------------- zero init for histogram/cursor ----------------
__global__ void zero_kernel(int* __restrict__ count, int* __restrict__ cursor, int n) {
    int i = blockIdx.x * blockDim.x + threadIdx.x;
    if (i < n) { count[i] = 0; cursor[i] = 0; }
}

// ---------------- per-atom MLP: t = silu(s@W1+b1)@W2 + b2 ----------------
// 1 wave per block, MLP_A atoms register-blocked: each weight element loaded
// once per block and reused across MLP_A atoms.
__global__ __launch_bounds__(64) void mlp_kernel(
    const float* __restrict__ s, const float* __restrict__ W1,
    const float* __restrict__ b1, const float* __restrict__ W2,
    const float* __restrict__ b2, float* __restrict__ t, int n_atoms) {
    __shared__ float s_lds[MLP_A][FDIM];
    __shared__ float h_lds[MLP_A][FDIM];
    const int f = threadIdx.x;
    const int atom0 = blockIdx.x * MLP_A;

#pragma unroll
    for (int a = 0; a < MLP_A; ++a) {
        int atom = atom0 + a;
        int ac = atom < n_atoms ? atom : (n_atoms - 1);
        s_lds[a][f] = s[(size_t)ac * FDIM + f];
    }
    __syncthreads();

    float acc[MLP_A];
#pragma unroll
    for (int a = 0; a < MLP_A; ++a) acc[a] = b1[f];
    for (int k = 0; k < FDIM; ++k) {
        float w = W1[k * FDIM + f];
#pragma unroll
        for (int a = 0; a < MLP_A; ++a) acc[a] = fmaf(s_lds[a][k], w, acc[a]);
    }
#pragma unroll
    for (int a = 0; a < MLP_A; ++a)
        h_lds[a][f] = acc[a] / (1.0f + __expf(-acc[a]));
    __syncthreads();

    float o0[MLP_A], o1[MLP_A], o2[MLP_A];
#pragma unroll
    for (int a = 0; a < MLP_A; ++a) {
        o0[a] = b2[f]; o1[a] = b2[FDIM + f]; o2[a] = b2[2 * FDIM + f];
    }
    for (int k = 0; k < FDIM; ++k) {
        float w0 = W2[k * TFDIM + f];
        float w1 = W2[k * TFDIM + FDIM + f];
        float w2 = W2[k * TFDIM + 2 * FDIM + f];
#pragma unroll
        for (int a = 0; a < MLP_A; ++a) {
            float h = h_lds[a][k];
            o0[a] = fmaf(h, w0, o0[a]);
            o1[a] = fmaf(h, w1, o1[a]);
            o2[a] = fmaf(h, w2, o2[a]);
        }
    }
#pragma unroll
    for (int a = 0; a < MLP_A; ++a) {
        int atom = atom0 + a;
        if (atom < n_atoms) {
            size_t base = (size_t)atom * TFDIM;
            t[base + f] = o0[a];
            t[base + FDIM + f] = o1[a];
            t[base + 2 * FDIM + f] = o2[a];
        }
    }
}

// ---------------- histogram of idx_i ----------------
__global__ void hist_kernel(const int* __restrict__ idx_i, int* __restrict__ count, int n_pairs) {
    for (int p = blockIdx.x * blockDim.x + threadIdx.x; p < n_pairs; p += gridDim.x * blockDim.x)
        atomicAdd(&count[idx_i[p]], 1);
}

// ---------------- single-block exclusive scan via wave scans ----------------
__global__ __launch_bounds__(1024) void scan_kernel(const int* __restrict__ count,
                                                    int* __restrict__ offsets, int n) {
    __shared__ int wsum[16];
    __shared__ int chunk_base;
    const int lane = threadIdx.x & 63;
    const int wid = threadIdx.x >> 6;
    if (threadIdx.x == 0) chunk_base = 0;
    __syncthreads();
    for (int base = 0; base < n; base += 1024) {
        int i = base + (int)threadIdx.x;
        int val = (i < n) ? count[i] : 0;
        int x = val;
#pragma unroll
        for (int off = 1; off < 64; off <<= 1) {
            int y = __shfl_up(x, off);
            if (lane >= off) x += y;
        }
        if (lane == 63) wsum[wid] = x;
        __syncthreads();
        if (wid == 0) {
            int w = (lane < 16) ? wsum[lane] : 0;
#pragma unroll
            for (int off = 1; off < 16; off <<= 1) {
                int y = __shfl_up(w, off);
                if (lane >= off) w += y;
            }
            if (lane < 16) wsum[lane] = w;
        }
        __syncthreads();
        int incl = x + (wid ? wsum[wid - 1] : 0) + chunk_base;
        if (i < n) offsets[i] = incl - val;
        int newbase = chunk_base + wsum[15];
        __syncthreads();
        if (threadIdx.x == 0) chunk_base = newbase;
        // next iteration's first __syncthreads orders this write vs. reads
    }
    __syncthreads();
    if (threadIdx.x == 0) offsets[n] = chunk_base;
}

// ---------------- scatter pair ids into per-atom buckets ----------------
__global__ void scatter_kernel(const int* __restrict__ idx_i, const int* __restrict__ offsets,
                               int* __restrict__ cursor, int* __restrict__ sorted, int n_pairs) {
    for (int p = blockIdx.x * blockDim.x + threadIdx.x; p < n_pairs; p += gridDim.x * blockDim.x) {
        int i = idx_i[p];
        int pos = offsets[i] + atomicAdd(&cursor[i], 1);
        sorted[pos] = p;
    }
}

// ---------------- main: one wave per atom i; 4 register accumulators ----------------
// Every W_ij/t/v element read exactly once. W_ij is stream-once -> nontemporal
// (keep L3 for the t/v gather tables). Outputs written nontemporal.
__global__ __launch_bounds__(64) void main_kernel(
    const float* __restrict__ s, const float* __restrict__ v,
    const float* __restrict__ Wij, const float* __restrict__ dir,
    const int* __restrict__ idx_j, const float* __restrict__ t,
    const int* __restrict__ offsets, const int* __restrict__ sorted,
    float* __restrict__ q_out, float* __restrict__ mu_out) {
    __shared__ int p_lds[64];
    __shared__ int j_lds[64];
    const int i = blockIdx.x;
    const int f = threadIdx.x;
    const int start = offsets[i];
    const int end = offsets[i + 1];

    float accq = 0.0f, acc0 = 0.0f, acc1 = 0.0f, acc2 = 0.0f;

    for (int cbase = start; cbase < end; cbase += 64) {
        int m = end - cbase;
        if (m > 64) m = 64;
        __syncthreads();
        if (f < m) {
            int p = sorted[cbase + f];
            p_lds[f] = p;
            j_lds[f] = idx_j[p];
        }
        __syncthreads();
        for (int k = 0; k < m; ++k) {
            int p = p_lds[k], j = j_lds[k];
            size_t pb = (size_t)p * TFDIM;
            size_t jb = (size_t)j * TFDIM;
            float w1 = __builtin_nontemporal_load(&Wij[pb + f]);
            float w2 = __builtin_nontemporal_load(&Wij[pb + FDIM + f]);
            float w3 = __builtin_nontemporal_load(&Wij[pb + 2 * FDIM + f]);
            float t1 = t[jb + f];
            float t2 = t[jb + FDIM + f];
            float t3 = t[jb + 2 * FDIM + f];
            float v0 = v[jb + f];
            float v1 = v[jb + FDIM + f];
            float v2 = v[jb + 2 * FDIM + f];
            float d0 = dir[3 * (size_t)p];
            float d1 = dir[3 * (size_t)p + 1];
            float d2 = dir[3 * (size_t)p + 2];
            float ds2 = w2 * t2;
            float ds3 = w3 * t3;
            accq = fmaf(w1, t1, accq);
            acc0 = fmaf(ds2, d0, fmaf(ds3, v0, acc0));
            acc1 = fmaf(ds2, d1, fmaf(ds3, v1, acc1));
            acc2 = fmaf(ds2, d2, fmaf(ds3, v2, acc2));
        }
    }

    size_t qb = (size_t)i * FDIM;
    size_t vb = (size_t)i * TFDIM;
    __builtin_nontemporal_store(s[qb + f] + accq, &q_out[qb + f]);
    __builtin_nontemporal_store(v[vb + f] + acc0, &mu_out[vb + f]);
    __builtin_nontemporal_store(v[vb + FDIM + f] + acc1, &mu_out[vb + FDIM + f]);
    __builtin_nontemporal_store(v[vb + 2 * FDIM + f] + acc2, &mu_out[vb + 2 * FDIM + f]);
}

extern "C" void kernel_launch(void* const* d_in, const int* in_sizes, int n_in,
                              void* d_out, int out_size, void* d_ws, size_t ws_size,
                              hipStream_t stream) {
    const float* s   = (const float*)d_in[0];   // [N,1,F]
    const float* v   = (const float*)d_in[1];   // [N,3,F]
    const float* Wij = (const float*)d_in[2];   // [P,3F]
    const float* dir = (const float*)d_in[3];   // [P,3]
    const int*   pl  = (const int*)d_in[4];     // [2,P]
    const float* W1  = (const float*)d_in[5];   // [F,F]
    const float* b1  = (const float*)d_in[6];   // [F]
    const float* W2  = (const float*)d_in[7];   // [F,3F]
    const float* b2  = (const float*)d_in[8];   // [3F]

    const int n_atoms = in_sizes[0] / FDIM;
    const int n_pairs = in_sizes[3] / 3;
    const int* idx_i = pl;
    const int* idx_j = pl + n_pairs;

    // workspace layout
    char* ws = (char*)d_ws;
    float* t = (float*)ws;                                   // n_atoms * 192 f32
    size_t t_bytes = (size_t)n_atoms * TFDIM * sizeof(float);
    int* count   = (int*)(ws + t_bytes);                     // n_atoms
    int* offsets = count + n_atoms;                          // n_atoms + 1
    int* cursor  = offsets + n_atoms + 1;                    // n_atoms
    int* sorted  = cursor + n_atoms;                         // n_pairs

    float* q_out  = (float*)d_out;                           // [N,1,F]
    float* mu_out = q_out + (size_t)n_atoms * FDIM;          // [N,3,F]

    zero_kernel<<<(n_atoms + 255) / 256, 256, 0, stream>>>(count, cursor, n_atoms);
    mlp_kernel<<<(n_atoms + MLP_A - 1) / MLP_A, 64, 0, stream>>>(s, W1, b1, W2, b2, t, n_atoms);
    hist_kernel<<<2048, 256, 0, stream>>>(idx_i, count, n_pairs);
    scan_kernel<<<1, 1024, 0, stream>>>(count, offsets, n_atoms);
    scatter_kernel<<<2048, 256, 0, stream>>>(idx_i, offsets, cursor, sorted, n_pairs);
    main_kernel<<<n_atoms, 64, 0, stream>>>(s, v, Wij, dir, idx_j, t, offsets, sorted,
                                            q_out, mu_out);
}

// Round 3
// 504.105 us; speedup vs baseline: 1.2942x; 1.0976x over previous
//
#include <hip/hip_runtime.h>

#define FDIM 64
#define TFDIM 192  // 3*F
#define MLP_A 8

// ---------------- zero init for histogram ----------------
__global__ void zero_kernel(int* __restrict__ count, int n) {
    int i = blockIdx.x * blockDim.x + threadIdx.x;
    if (i < n) count[i] = 0;
}

// ---------------- per-atom MLP: t = silu(s@W1+b1)@W2 + b2 ----------------
__global__ __launch_bounds__(64) void mlp_kernel(
    const float* __restrict__ s, const float* __restrict__ W1,
    const float* __restrict__ b1, const float* __restrict__ W2,
    const float* __restrict__ b2, float* __restrict__ t, int n_atoms) {
    __shared__ float s_lds[MLP_A][FDIM];
    __shared__ float h_lds[MLP_A][FDIM];
    const int f = threadIdx.x;
    const int atom0 = blockIdx.x * MLP_A;

#pragma unroll
    for (int a = 0; a < MLP_A; ++a) {
        int atom = atom0 + a;
        int ac = atom < n_atoms ? atom : (n_atoms - 1);
        s_lds[a][f] = s[(size_t)ac * FDIM + f];
    }
    __syncthreads();

    float acc[MLP_A];
#pragma unroll
    for (int a = 0; a < MLP_A; ++a) acc[a] = b1[f];
    for (int k = 0; k < FDIM; ++k) {
        float w = W1[k * FDIM + f];
#pragma unroll
        for (int a = 0; a < MLP_A; ++a) acc[a] = fmaf(s_lds[a][k], w, acc[a]);
    }
#pragma unroll
    for (int a = 0; a < MLP_A; ++a)
        h_lds[a][f] = acc[a] / (1.0f + __expf(-acc[a]));
    __syncthreads();

    float o0[MLP_A], o1[MLP_A], o2[MLP_A];
#pragma unroll
    for (int a = 0; a < MLP_A; ++a) {
        o0[a] = b2[f]; o1[a] = b2[FDIM + f]; o2[a] = b2[2 * FDIM + f];
    }
    for (int k = 0; k < FDIM; ++k) {
        float w0 = W2[k * TFDIM + f];
        float w1 = W2[k * TFDIM + FDIM + f];
        float w2 = W2[k * TFDIM + 2 * FDIM + f];
#pragma unroll
        for (int a = 0; a < MLP_A; ++a) {
            float h = h_lds[a][k];
            o0[a] = fmaf(h, w0, o0[a]);
            o1[a] = fmaf(h, w1, o1[a]);
            o2[a] = fmaf(h, w2, o2[a]);
        }
    }
#pragma unroll
    for (int a = 0; a < MLP_A; ++a) {
        int atom = atom0 + a;
        if (atom < n_atoms) {
            size_t base = (size_t)atom * TFDIM;
            t[base + f] = o0[a];
            t[base + FDIM + f] = o1[a];
            t[base + 2 * FDIM + f] = o2[a];
        }
    }
}

// ---------------- histogram of idx_i (int4 loads) ----------------
__global__ void hist_kernel(const int* __restrict__ idx_i, int* __restrict__ count, int n_pairs) {
    int n4 = n_pairs >> 2;
    for (int g = blockIdx.x * blockDim.x + threadIdx.x; g < n4; g += gridDim.x * blockDim.x) {
        int4 ii = ((const int4*)idx_i)[g];
        atomicAdd(&count[ii.x], 1);
        atomicAdd(&count[ii.y], 1);
        atomicAdd(&count[ii.z], 1);
        atomicAdd(&count[ii.w], 1);
    }
    if (blockIdx.x == 0 && threadIdx.x == 0) {
        for (int p = n4 << 2; p < n_pairs; ++p) atomicAdd(&count[idx_i[p]], 1);
    }
}

// ---------------- hierarchical exclusive scan ----------------
__global__ __launch_bounds__(1024) void scan_local(const int* __restrict__ count,
                                                   int* __restrict__ offsets,
                                                   int* __restrict__ bsum, int n) {
    __shared__ int wsum[16];
    const int tid = threadIdx.x;
    const int lane = tid & 63, wid = tid >> 6;
    int i = blockIdx.x * 1024 + tid;
    int val = (i < n) ? count[i] : 0;
    int x = val;
#pragma unroll
    for (int off = 1; off < 64; off <<= 1) {
        int y = __shfl_up(x, off);
        if (lane >= off) x += y;
    }
    if (lane == 63) wsum[wid] = x;
    __syncthreads();
    if (wid == 0) {
        int w = (lane < 16) ? wsum[lane] : 0;
#pragma unroll
        for (int off = 1; off < 16; off <<= 1) {
            int y = __shfl_up(w, off);
            if (lane >= off) w += y;
        }
        if (lane < 16) wsum[lane] = w;
    }
    __syncthreads();
    int excl = x - val + (wid ? wsum[wid - 1] : 0);
    if (i < n) offsets[i] = excl;
    if (tid == 0) bsum[blockIdx.x] = wsum[15];
}

__global__ __launch_bounds__(64) void scan_tops(int* __restrict__ bsum,
                                                int* __restrict__ offsets, int nb, int n) {
    const int lane = threadIdx.x;
    int val = (lane < nb) ? bsum[lane] : 0;
    int x = val;
#pragma unroll
    for (int off = 1; off < 64; off <<= 1) {
        int y = __shfl_up(x, off);
        if (lane >= off) x += y;
    }
    if (lane < nb) bsum[lane] = x - val;
    if (lane == 63) offsets[n] = x;
}

__global__ void scan_add(int* __restrict__ offsets, const int* __restrict__ bsum, int n) {
    int i = blockIdx.x * blockDim.x + threadIdx.x;
    if (i < n) offsets[i] += bsum[i >> 10];
}

// ---------------- scatter packed (p, j) into buckets; bumps offsets ----------------
__global__ void scatter_kernel(const int* __restrict__ idx_i, const int* __restrict__ idx_j,
                               int* __restrict__ offsets, int2* __restrict__ sorted2,
                               int n_pairs) {
    int n4 = n_pairs >> 2;
    for (int g = blockIdx.x * blockDim.x + threadIdx.x; g < n4; g += gridDim.x * blockDim.x) {
        int4 ii = ((const int4*)idx_i)[g];
        int4 jj = ((const int4*)idx_j)[g];
        int p0 = 4 * g;
        int pos;
        pos = atomicAdd(&offsets[ii.x], 1); sorted2[pos] = make_int2(p0 + 0, jj.x);
        pos = atomicAdd(&offsets[ii.y], 1); sorted2[pos] = make_int2(p0 + 1, jj.y);
        pos = atomicAdd(&offsets[ii.z], 1); sorted2[pos] = make_int2(p0 + 2, jj.z);
        pos = atomicAdd(&offsets[ii.w], 1); sorted2[pos] = make_int2(p0 + 3, jj.w);
    }
    if (blockIdx.x == 0 && threadIdx.x == 0) {
        for (int p = n4 << 2; p < n_pairs; ++p) {
            int pos = atomicAdd(&offsets[idx_i[p]], 1);
            sorted2[pos] = make_int2(p, idx_j[p]);
        }
    }
}

// ---------------- main: one wave per atom; SGPR indices via readlane ----------------
// After scatter, offsets[i] == bucket END; start = end - count[i].
__global__ __launch_bounds__(64) void main_kernel(
    const float* __restrict__ s, const float* __restrict__ v,
    const float* __restrict__ Wij, const float* __restrict__ dir,
    const float* __restrict__ t, const int* __restrict__ offsets_post,
    const int* __restrict__ count, const int2* __restrict__ sorted2,
    float* __restrict__ q_out, float* __restrict__ mu_out) {
    const int i = blockIdx.x;
    const int f = threadIdx.x;
    const int end = offsets_post[i];
    const int cnt = count[i];
    const int start = end - cnt;

    float accq = 0.f, acc0 = 0.f, acc1 = 0.f, acc2 = 0.f;
    for (int cbase = start; cbase < end; cbase += 64) {
        int m = end - cbase;
        if (m > 64) m = 64;
        int idx = cbase + f;
        int2 pj = sorted2[idx < end ? idx : start];
#pragma unroll 2
        for (int k = 0; k < m; ++k) {
            int p = __builtin_amdgcn_readlane(pj.x, k);
            int j = __builtin_amdgcn_readlane(pj.y, k);
            const float* wp = Wij + (size_t)p * TFDIM;
            const float* tp = t + (size_t)j * TFDIM;
            const float* vp = v + (size_t)j * TFDIM;
            float w1 = __builtin_nontemporal_load(wp + f);
            float w2 = __builtin_nontemporal_load(wp + FDIM + f);
            float w3 = __builtin_nontemporal_load(wp + 2 * FDIM + f);
            float t1 = tp[f];
            float t2 = tp[FDIM + f];
            float t3 = tp[2 * FDIM + f];
            float v0 = vp[f];
            float v1 = vp[FDIM + f];
            float v2 = vp[2 * FDIM + f];
            float d0 = dir[3 * (size_t)p];
            float d1 = dir[3 * (size_t)p + 1];
            float d2 = dir[3 * (size_t)p + 2];
            float ds2 = w2 * t2;
            float ds3 = w3 * t3;
            accq = fmaf(w1, t1, accq);
            acc0 = fmaf(ds2, d0, fmaf(ds3, v0, acc0));
            acc1 = fmaf(ds2, d1, fmaf(ds3, v1, acc1));
            acc2 = fmaf(ds2, d2, fmaf(ds3, v2, acc2));
        }
    }

    size_t qb = (size_t)i * FDIM;
    size_t vb = (size_t)i * TFDIM;
    __builtin_nontemporal_store(s[qb + f] + accq, &q_out[qb + f]);
    __builtin_nontemporal_store(v[vb + f] + acc0, &mu_out[vb + f]);
    __builtin_nontemporal_store(v[vb + FDIM + f] + acc1, &mu_out[vb + FDIM + f]);
    __builtin_nontemporal_store(v[vb + 2 * FDIM + f] + acc2, &mu_out[vb + 2 * FDIM + f]);
}

extern "C" void kernel_launch(void* const* d_in, const int* in_sizes, int n_in,
                              void* d_out, int out_size, void* d_ws, size_t ws_size,
                              hipStream_t stream) {
    const float* s   = (const float*)d_in[0];   // [N,1,F]
    const float* v   = (const float*)d_in[1];   // [N,3,F]
    const float* Wij = (const float*)d_in[2];   // [P,3F]
    const float* dir = (const float*)d_in[3];   // [P,3]
    const int*   pl  = (const int*)d_in[4];     // [2,P]
    const float* W1  = (const float*)d_in[5];
    const float* b1  = (const float*)d_in[6];
    const float* W2  = (const float*)d_in[7];
    const float* b2  = (const float*)d_in[8];

    const int n_atoms = in_sizes[0] / FDIM;
    const int n_pairs = in_sizes[3] / 3;
    const int* idx_i = pl;
    const int* idx_j = pl + n_pairs;

    // workspace layout
    char* ws = (char*)d_ws;
    float* t = (float*)ws;                                   // n_atoms*192 f32
    size_t t_bytes = (size_t)n_atoms * TFDIM * sizeof(float);
    int* count   = (int*)(ws + t_bytes);                     // n_atoms
    int* offsets = count + n_atoms;                          // n_atoms + 1
    int* bsum    = offsets + n_atoms + 1;                    // 64
    int2* sorted2 = (int2*)(bsum + 64);                      // n_pairs int2
    // align sorted2 to 8B: bsum+64 is 4B-aligned offset from 8B-aligned base;
    // t_bytes and the int arrays sum to (192*n + 2n + 65)*4 — force alignment:
    sorted2 = (int2*)((((size_t)(bsum + 64)) + 15) & ~(size_t)15);

    float* q_out  = (float*)d_out;                           // [N,1,F]
    float* mu_out = q_out + (size_t)n_atoms * FDIM;          // [N,3,F]

    const int nb = (n_atoms + 1023) / 1024;

    zero_kernel<<<(n_atoms + 255) / 256, 256, 0, stream>>>(count, n_atoms);
    mlp_kernel<<<(n_atoms + MLP_A - 1) / MLP_A, 64, 0, stream>>>(s, W1, b1, W2, b2, t, n_atoms);
    hist_kernel<<<1024, 256, 0, stream>>>(idx_i, count, n_pairs);
    scan_local<<<nb, 1024, 0, stream>>>(count, offsets, bsum, n_atoms);
    scan_tops<<<1, 64, 0, stream>>>(bsum, offsets, nb, n_atoms);
    scan_add<<<(n_atoms + 1023) / 1024, 1024, 0, stream>>>(offsets, bsum, n_atoms);
    scatter_kernel<<<1024, 256, 0, stream>>>(idx_i, idx_j, offsets, sorted2, n_pairs);
    main_kernel<<<n_atoms, 64, 0, stream>>>(s, v, Wij, dir, t, offsets, count, sorted2,
                                            q_out, mu_out);
}

// Round 5
// 387.356 us; speedup vs baseline: 1.6842x; 1.3014x over previous
//
#include <hip/hip_runtime.h>

#define FDIM 64
#define TFDIM 192  // 3*F
#define MLP_A 8

static __device__ __forceinline__ float bf2f(unsigned short u) {
    union { unsigned int i; float f; } x;
    x.i = ((unsigned int)u) << 16;
    return x.f;
}
// f32 -> bf16 with round-to-nearest-even (no header dependence)
static __device__ __forceinline__ unsigned short f2bf(float f) {
    unsigned int u = __float_as_uint(f);
    unsigned int rounding = 0x7fffu + ((u >> 16) & 1u);
    return (unsigned short)((u + rounding) >> 16);
}

// ---------------- zero init for histogram ----------------
__global__ void zero_kernel(int* __restrict__ count, int n) {
    int i = blockIdx.x * blockDim.x + threadIdx.x;
    if (i < n) count[i] = 0;
}

// ---------------- v (f32) -> v16 (bf16) ----------------
__global__ void cvt_kernel(const float* __restrict__ v, unsigned short* __restrict__ v16,
                           int n_elems) {
    int g = blockIdx.x * blockDim.x + threadIdx.x;
    int n4 = n_elems >> 2;
    if (g < n4) {
        float4 x = ((const float4*)v)[g];
        ushort4 y;
        y.x = f2bf(x.x); y.y = f2bf(x.y); y.z = f2bf(x.z); y.w = f2bf(x.w);
        ((ushort4*)v16)[g] = y;
    }
}

// ---------------- per-atom MLP: t16 = bf16(silu(s@W1+b1)@W2 + b2) ----------------
__global__ __launch_bounds__(64) void mlp_kernel(
    const float* __restrict__ s, const float* __restrict__ W1,
    const float* __restrict__ b1, const float* __restrict__ W2,
    const float* __restrict__ b2, unsigned short* __restrict__ t16, int n_atoms) {
    __shared__ float s_lds[MLP_A][FDIM];
    __shared__ float h_lds[MLP_A][FDIM];
    const int f = threadIdx.x;
    const int atom0 = blockIdx.x * MLP_A;

#pragma unroll
    for (int a = 0; a < MLP_A; ++a) {
        int atom = atom0 + a;
        int ac = atom < n_atoms ? atom : (n_atoms - 1);
        s_lds[a][f] = s[(size_t)ac * FDIM + f];
    }
    __syncthreads();

    float acc[MLP_A];
#pragma unroll
    for (int a = 0; a < MLP_A; ++a) acc[a] = b1[f];
    for (int k = 0; k < FDIM; ++k) {
        float w = W1[k * FDIM + f];
#pragma unroll
        for (int a = 0; a < MLP_A; ++a) acc[a] = fmaf(s_lds[a][k], w, acc[a]);
    }
#pragma unroll
    for (int a = 0; a < MLP_A; ++a)
        h_lds[a][f] = acc[a] / (1.0f + __expf(-acc[a]));
    __syncthreads();

    float o0[MLP_A], o1[MLP_A], o2[MLP_A];
#pragma unroll
    for (int a = 0; a < MLP_A; ++a) {
        o0[a] = b2[f]; o1[a] = b2[FDIM + f]; o2[a] = b2[2 * FDIM + f];
    }
    for (int k = 0; k < FDIM; ++k) {
        float w0 = W2[k * TFDIM + f];
        float w1 = W2[k * TFDIM + FDIM + f];
        float w2 = W2[k * TFDIM + 2 * FDIM + f];
#pragma unroll
        for (int a = 0; a < MLP_A; ++a) {
            float h = h_lds[a][k];
            o0[a] = fmaf(h, w0, o0[a]);
            o1[a] = fmaf(h, w1, o1[a]);
            o2[a] = fmaf(h, w2, o2[a]);
        }
    }
#pragma unroll
    for (int a = 0; a < MLP_A; ++a) {
        int atom = atom0 + a;
        if (atom < n_atoms) {
            size_t base = (size_t)atom * TFDIM;
            t16[base + f] = f2bf(o0[a]);
            t16[base + FDIM + f] = f2bf(o1[a]);
            t16[base + 2 * FDIM + f] = f2bf(o2[a]);
        }
    }
}

// ---------------- histogram of idx_i (int4 loads) ----------------
__global__ void hist_kernel(const int* __restrict__ idx_i, int* __restrict__ count, int n_pairs) {
    int n4 = n_pairs >> 2;
    for (int g = blockIdx.x * blockDim.x + threadIdx.x; g < n4; g += gridDim.x * blockDim.x) {
        int4 ii = ((const int4*)idx_i)[g];
        atomicAdd(&count[ii.x], 1);
        atomicAdd(&count[ii.y], 1);
        atomicAdd(&count[ii.z], 1);
        atomicAdd(&count[ii.w], 1);
    }
    if (blockIdx.x == 0 && threadIdx.x == 0) {
        for (int p = n4 << 2; p < n_pairs; ++p) atomicAdd(&count[idx_i[p]], 1);
    }
}

// ---------------- hierarchical exclusive scan ----------------
__global__ __launch_bounds__(1024) void scan_local(const int* __restrict__ count,
                                                   int* __restrict__ offsets,
                                                   int* __restrict__ bsum, int n) {
    __shared__ int wsum[16];
    const int tid = threadIdx.x;
    const int lane = tid & 63, wid = tid >> 6;
    int i = blockIdx.x * 1024 + tid;
    int val = (i < n) ? count[i] : 0;
    int x = val;
#pragma unroll
    for (int off = 1; off < 64; off <<= 1) {
        int y = __shfl_up(x, off);
        if (lane >= off) x += y;
    }
    if (lane == 63) wsum[wid] = x;
    __syncthreads();
    if (wid == 0) {
        int w = (lane < 16) ? wsum[lane] : 0;
#pragma unroll
        for (int off = 1; off < 16; off <<= 1) {
            int y = __shfl_up(w, off);
            if (lane >= off) w += y;
        }
        if (lane < 16) wsum[lane] = w;
    }
    __syncthreads();
    int excl = x - val + (wid ? wsum[wid - 1] : 0);
    if (i < n) offsets[i] = excl;
    if (tid == 0) bsum[blockIdx.x] = wsum[15];
}

__global__ __launch_bounds__(64) void scan_tops(int* __restrict__ bsum,
                                                int* __restrict__ offsets, int nb, int n) {
    const int lane = threadIdx.x;
    int val = (lane < nb) ? bsum[lane] : 0;
    int x = val;
#pragma unroll
    for (int off = 1; off < 64; off <<= 1) {
        int y = __shfl_up(x, off);
        if (lane >= off) x += y;
    }
    if (lane < nb) bsum[lane] = x - val;
    if (lane == 63) offsets[n] = x;
}

__global__ void scan_add(int* __restrict__ offsets, const int* __restrict__ bsum, int n) {
    int i = blockIdx.x * blockDim.x + threadIdx.x;
    if (i < n) offsets[i] += bsum[i >> 10];
}

// ---------------- scatter (p, j) + dir into buckets; bumps offsets ----------------
__global__ void scatter_kernel(const int* __restrict__ idx_i, const int* __restrict__ idx_j,
                               const float* __restrict__ dir, int* __restrict__ offsets,
                               int2* __restrict__ pjbuf, float4* __restrict__ dbuf,
                               int n_pairs) {
    int n4 = n_pairs >> 2;
    const float4* dir4 = (const float4*)dir;
    for (int g = blockIdx.x * blockDim.x + threadIdx.x; g < n4; g += gridDim.x * blockDim.x) {
        int4 ii = ((const int4*)idx_i)[g];
        int4 jj = ((const int4*)idx_j)[g];
        float4 da = dir4[3 * g];
        float4 db = dir4[3 * g + 1];
        float4 dc = dir4[3 * g + 2];
        int p0 = 4 * g;
        int pos;
        pos = atomicAdd(&offsets[ii.x], 1);
        pjbuf[pos] = make_int2(p0 + 0, jj.x);
        dbuf[pos] = make_float4(da.x, da.y, da.z, 0.f);
        pos = atomicAdd(&offsets[ii.y], 1);
        pjbuf[pos] = make_int2(p0 + 1, jj.y);
        dbuf[pos] = make_float4(da.w, db.x, db.y, 0.f);
        pos = atomicAdd(&offsets[ii.z], 1);
        pjbuf[pos] = make_int2(p0 + 2, jj.z);
        dbuf[pos] = make_float4(db.z, db.w, dc.x, 0.f);
        pos = atomicAdd(&offsets[ii.w], 1);
        pjbuf[pos] = make_int2(p0 + 3, jj.w);
        dbuf[pos] = make_float4(dc.y, dc.z, dc.w, 0.f);
    }
    if (blockIdx.x == 0 && threadIdx.x == 0) {
        for (int p = n4 << 2; p < n_pairs; ++p) {
            int pos = atomicAdd(&offsets[idx_i[p]], 1);
            pjbuf[pos] = make_int2(p, idx_j[p]);
            dbuf[pos] = make_float4(dir[3 * (size_t)p], dir[3 * (size_t)p + 1],
                                    dir[3 * (size_t)p + 2], 0.f);
        }
    }
}

// ---------------- main: one wave per atom; SGPR indices via readlane ----------------
__global__ __launch_bounds__(64) void main_kernel(
    const float* __restrict__ s, const float* __restrict__ v,
    const float* __restrict__ Wij, const unsigned short* __restrict__ v16,
    const unsigned short* __restrict__ t16, const int* __restrict__ offsets_post,
    const int* __restrict__ count, const int2* __restrict__ pjbuf,
    const float4* __restrict__ dbuf,
    float* __restrict__ q_out, float* __restrict__ mu_out) {
    const int i = blockIdx.x;
    const int f = threadIdx.x;
    const int end = offsets_post[i];
    const int cnt = count[i];
    const int start = end - cnt;

    float accq = 0.f, acc0 = 0.f, acc1 = 0.f, acc2 = 0.f;
    for (int cbase = start; cbase < end; cbase += 64) {
        int m = end - cbase;
        if (m > 64) m = 64;
        int idx = cbase + f;
        int sidx = idx < end ? idx : start;
        int2 pj = pjbuf[sidx];
        float4 dd = dbuf[sidx];
#pragma unroll 2
        for (int k = 0; k < m; ++k) {
            int p = __builtin_amdgcn_readlane(pj.x, k);
            int j = __builtin_amdgcn_readlane(pj.y, k);
            float d0 = __uint_as_float(__builtin_amdgcn_readlane(__float_as_uint(dd.x), k));
            float d1 = __uint_as_float(__builtin_amdgcn_readlane(__float_as_uint(dd.y), k));
            float d2 = __uint_as_float(__builtin_amdgcn_readlane(__float_as_uint(dd.z), k));
            const float* wp = Wij + (size_t)p * TFDIM;
            const unsigned short* tp = t16 + (size_t)j * TFDIM;
            const unsigned short* vp = v16 + (size_t)j * TFDIM;
            float w1 = __builtin_nontemporal_load(wp + f);
            float w2 = __builtin_nontemporal_load(wp + FDIM + f);
            float w3 = __builtin_nontemporal_load(wp + 2 * FDIM + f);
            float t1 = bf2f(tp[f]);
            float t2 = bf2f(tp[FDIM + f]);
            float t3 = bf2f(tp[2 * FDIM + f]);
            float v0 = bf2f(vp[f]);
            float v1 = bf2f(vp[FDIM + f]);
            float v2 = bf2f(vp[2 * FDIM + f]);
            float ds2 = w2 * t2;
            float ds3 = w3 * t3;
            accq = fmaf(w1, t1, accq);
            acc0 = fmaf(ds2, d0, fmaf(ds3, v0, acc0));
            acc1 = fmaf(ds2, d1, fmaf(ds3, v1, acc1));
            acc2 = fmaf(ds2, d2, fmaf(ds3, v2, acc2));
        }
    }

    size_t qb = (size_t)i * FDIM;
    size_t vb = (size_t)i * TFDIM;
    __builtin_nontemporal_store(s[qb + f] + accq, &q_out[qb + f]);
    __builtin_nontemporal_store(v[vb + f] + acc0, &mu_out[vb + f]);
    __builtin_nontemporal_store(v[vb + FDIM + f] + acc1, &mu_out[vb + FDIM + f]);
    __builtin_nontemporal_store(v[vb + 2 * FDIM + f] + acc2, &mu_out[vb + 2 * FDIM + f]);
}

extern "C" void kernel_launch(void* const* d_in, const int* in_sizes, int n_in,
                              void* d_out, int out_size, void* d_ws, size_t ws_size,
                              hipStream_t stream) {
    const float* s   = (const float*)d_in[0];   // [N,1,F]
    const float* v   = (const float*)d_in[1];   // [N,3,F]
    const float* Wij = (const float*)d_in[2];   // [P,3F]
    const float* dir = (const float*)d_in[3];   // [P,3]
    const int*   pl  = (const int*)d_in[4];     // [2,P]
    const float* W1  = (const float*)d_in[5];
    const float* b1  = (const float*)d_in[6];
    const float* W2  = (const float*)d_in[7];
    const float* b2  = (const float*)d_in[8];

    const int n_atoms = in_sizes[0] / FDIM;
    const int n_pairs = in_sizes[3] / 3;
    const int* idx_i = pl;
    const int* idx_j = pl + n_pairs;

    // workspace layout (16B-aligned slices)
    char* ws = (char*)d_ws;
    size_t off = 0;
    auto alloc = [&](size_t bytes) {
        void* ptr = ws + off;
        off = (off + bytes + 15) & ~(size_t)15;
        return ptr;
    };
    unsigned short* t16 = (unsigned short*)alloc((size_t)n_atoms * TFDIM * 2);
    unsigned short* v16 = (unsigned short*)alloc((size_t)n_atoms * TFDIM * 2);
    int* count   = (int*)alloc((size_t)n_atoms * 4);
    int* offsets = (int*)alloc(((size_t)n_atoms + 1) * 4);
    int* bsum    = (int*)alloc(64 * 4);
    int2* pjbuf  = (int2*)alloc((size_t)n_pairs * 8);
    float4* dbuf = (float4*)alloc((size_t)n_pairs * 16);

    float* q_out  = (float*)d_out;                           // [N,1,F]
    float* mu_out = q_out + (size_t)n_atoms * FDIM;          // [N,3,F]

    const int nb = (n_atoms + 1023) / 1024;
    const int nv = n_atoms * TFDIM;

    zero_kernel<<<(n_atoms + 255) / 256, 256, 0, stream>>>(count, n_atoms);
    cvt_kernel<<<((nv >> 2) + 255) / 256, 256, 0, stream>>>(v, v16, nv);
    mlp_kernel<<<(n_atoms + MLP_A - 1) / MLP_A, 64, 0, stream>>>(s, W1, b1, W2, b2, t16, n_atoms);
    hist_kernel<<<1024, 256, 0, stream>>>(idx_i, count, n_pairs);
    scan_local<<<nb, 1024, 0, stream>>>(count, offsets, bsum, n_atoms);
    scan_tops<<<1, 64, 0, stream>>>(bsum, offsets, nb, n_atoms);
    scan_add<<<(n_atoms + 1023) / 1024, 1024, 0, stream>>>(offsets, bsum, n_atoms);
    scatter_kernel<<<1024, 256, 0, stream>>>(idx_i, idx_j, dir, offsets, pjbuf, dbuf, n_pairs);
    main_kernel<<<n_atoms, 64, 0, stream>>>(s, v, Wij, v16, t16, offsets, count, pjbuf, dbuf,
                                            q_out, mu_out);
}

// Round 6
// 384.251 us; speedup vs baseline: 1.6979x; 1.0081x over previous
//
#include <hip/hip_runtime.h>

#define FDIM 64
#define TFDIM 192  // 3*F
#define MLP_A 8

static __device__ __forceinline__ float bf2f(unsigned short u) {
    union { unsigned int i; float f; } x;
    x.i = ((unsigned int)u) << 16;
    return x.f;
}
// f32 -> bf16 with round-to-nearest-even (no header dependence)
static __device__ __forceinline__ unsigned short f2bf(float f) {
    unsigned int u = __float_as_uint(f);
    unsigned int rounding = 0x7fffu + ((u >> 16) & 1u);
    return (unsigned short)((u + rounding) >> 16);
}

// ---------------- zero init for histogram ----------------
__global__ void zero_kernel(int* __restrict__ count, int n) {
    int i = blockIdx.x * blockDim.x + threadIdx.x;
    if (i < n) count[i] = 0;
}

// ---------------- v (f32) -> v16 (bf16) ----------------
__global__ void cvt_kernel(const float* __restrict__ v, unsigned short* __restrict__ v16,
                           int n_elems) {
    int g = blockIdx.x * blockDim.x + threadIdx.x;
    int n4 = n_elems >> 2;
    if (g < n4) {
        float4 x = ((const float4*)v)[g];
        ushort4 y;
        y.x = f2bf(x.x); y.y = f2bf(x.y); y.z = f2bf(x.z); y.w = f2bf(x.w);
        ((ushort4*)v16)[g] = y;
    }
}

// ---------------- per-atom MLP: t16 = bf16(silu(s@W1+b1)@W2 + b2) ----------------
__global__ __launch_bounds__(64) void mlp_kernel(
    const float* __restrict__ s, const float* __restrict__ W1,
    const float* __restrict__ b1, const float* __restrict__ W2,
    const float* __restrict__ b2, unsigned short* __restrict__ t16, int n_atoms) {
    __shared__ float s_lds[MLP_A][FDIM];
    __shared__ float h_lds[MLP_A][FDIM];
    const int f = threadIdx.x;
    const int atom0 = blockIdx.x * MLP_A;

#pragma unroll
    for (int a = 0; a < MLP_A; ++a) {
        int atom = atom0 + a;
        int ac = atom < n_atoms ? atom : (n_atoms - 1);
        s_lds[a][f] = s[(size_t)ac * FDIM + f];
    }
    __syncthreads();

    float acc[MLP_A];
#pragma unroll
    for (int a = 0; a < MLP_A; ++a) acc[a] = b1[f];
    for (int k = 0; k < FDIM; ++k) {
        float w = W1[k * FDIM + f];
#pragma unroll
        for (int a = 0; a < MLP_A; ++a) acc[a] = fmaf(s_lds[a][k], w, acc[a]);
    }
#pragma unroll
    for (int a = 0; a < MLP_A; ++a)
        h_lds[a][f] = acc[a] / (1.0f + __expf(-acc[a]));
    __syncthreads();

    float o0[MLP_A], o1[MLP_A], o2[MLP_A];
#pragma unroll
    for (int a = 0; a < MLP_A; ++a) {
        o0[a] = b2[f]; o1[a] = b2[FDIM + f]; o2[a] = b2[2 * FDIM + f];
    }
    for (int k = 0; k < FDIM; ++k) {
        float w0 = W2[k * TFDIM + f];
        float w1 = W2[k * TFDIM + FDIM + f];
        float w2 = W2[k * TFDIM + 2 * FDIM + f];
#pragma unroll
        for (int a = 0; a < MLP_A; ++a) {
            float h = h_lds[a][k];
            o0[a] = fmaf(h, w0, o0[a]);
            o1[a] = fmaf(h, w1, o1[a]);
            o2[a] = fmaf(h, w2, o2[a]);
        }
    }
#pragma unroll
    for (int a = 0; a < MLP_A; ++a) {
        int atom = atom0 + a;
        if (atom < n_atoms) {
            size_t base = (size_t)atom * TFDIM;
            t16[base + f] = f2bf(o0[a]);
            t16[base + FDIM + f] = f2bf(o1[a]);
            t16[base + 2 * FDIM + f] = f2bf(o2[a]);
        }
    }
}

// ---------------- histogram of idx_i (int4 loads) ----------------
__global__ void hist_kernel(const int* __restrict__ idx_i, int* __restrict__ count, int n_pairs) {
    int n4 = n_pairs >> 2;
    for (int g = blockIdx.x * blockDim.x + threadIdx.x; g < n4; g += gridDim.x * blockDim.x) {
        int4 ii = ((const int4*)idx_i)[g];
        atomicAdd(&count[ii.x], 1);
        atomicAdd(&count[ii.y], 1);
        atomicAdd(&count[ii.z], 1);
        atomicAdd(&count[ii.w], 1);
    }
    if (blockIdx.x == 0 && threadIdx.x == 0) {
        for (int p = n4 << 2; p < n_pairs; ++p) atomicAdd(&count[idx_i[p]], 1);
    }
}

// ---------------- hierarchical exclusive scan ----------------
__global__ __launch_bounds__(1024) void scan_local(const int* __restrict__ count,
                                                   int* __restrict__ offsets,
                                                   int* __restrict__ bsum, int n) {
    __shared__ int wsum[16];
    const int tid = threadIdx.x;
    const int lane = tid & 63, wid = tid >> 6;
    int i = blockIdx.x * 1024 + tid;
    int val = (i < n) ? count[i] : 0;
    int x = val;
#pragma unroll
    for (int off = 1; off < 64; off <<= 1) {
        int y = __shfl_up(x, off);
        if (lane >= off) x += y;
    }
    if (lane == 63) wsum[wid] = x;
    __syncthreads();
    if (wid == 0) {
        int w = (lane < 16) ? wsum[lane] : 0;
#pragma unroll
        for (int off = 1; off < 16; off <<= 1) {
            int y = __shfl_up(w, off);
            if (lane >= off) w += y;
        }
        if (lane < 16) wsum[lane] = w;
    }
    __syncthreads();
    int excl = x - val + (wid ? wsum[wid - 1] : 0);
    if (i < n) offsets[i] = excl;
    if (tid == 0) bsum[blockIdx.x] = wsum[15];
}

__global__ __launch_bounds__(64) void scan_tops(int* __restrict__ bsum,
                                                int* __restrict__ offsets, int nb, int n) {
    const int lane = threadIdx.x;
    int val = (lane < nb) ? bsum[lane] : 0;
    int x = val;
#pragma unroll
    for (int off = 1; off < 64; off <<= 1) {
        int y = __shfl_up(x, off);
        if (lane >= off) x += y;
    }
    if (lane < nb) bsum[lane] = x - val;
    if (lane == 63) offsets[n] = x;
}

__global__ void scan_add(int* __restrict__ offsets, const int* __restrict__ bsum, int n) {
    int i = blockIdx.x * blockDim.x + threadIdx.x;
    if (i < n) offsets[i] += bsum[i >> 10];
}

// ---------------- scatter (p, j) + dir into buckets; bumps offsets ----------------
__global__ void scatter_kernel(const int* __restrict__ idx_i, const int* __restrict__ idx_j,
                               const float* __restrict__ dir, int* __restrict__ offsets,
                               int2* __restrict__ pjbuf, float4* __restrict__ dbuf,
                               int n_pairs) {
    int n4 = n_pairs >> 2;
    const float4* dir4 = (const float4*)dir;
    for (int g = blockIdx.x * blockDim.x + threadIdx.x; g < n4; g += gridDim.x * blockDim.x) {
        int4 ii = ((const int4*)idx_i)[g];
        int4 jj = ((const int4*)idx_j)[g];
        float4 da = dir4[3 * g];
        float4 db = dir4[3 * g + 1];
        float4 dc = dir4[3 * g + 2];
        int p0 = 4 * g;
        int pos;
        pos = atomicAdd(&offsets[ii.x], 1);
        pjbuf[pos] = make_int2(p0 + 0, jj.x);
        dbuf[pos] = make_float4(da.x, da.y, da.z, 0.f);
        pos = atomicAdd(&offsets[ii.y], 1);
        pjbuf[pos] = make_int2(p0 + 1, jj.y);
        dbuf[pos] = make_float4(da.w, db.x, db.y, 0.f);
        pos = atomicAdd(&offsets[ii.z], 1);
        pjbuf[pos] = make_int2(p0 + 2, jj.z);
        dbuf[pos] = make_float4(db.z, db.w, dc.x, 0.f);
        pos = atomicAdd(&offsets[ii.w], 1);
        pjbuf[pos] = make_int2(p0 + 3, jj.w);
        dbuf[pos] = make_float4(dc.y, dc.z, dc.w, 0.f);
    }
    if (blockIdx.x == 0 && threadIdx.x == 0) {
        for (int p = n4 << 2; p < n_pairs; ++p) {
            int pos = atomicAdd(&offsets[idx_i[p]], 1);
            pjbuf[pos] = make_int2(p, idx_j[p]);
            dbuf[pos] = make_float4(dir[3 * (size_t)p], dir[3 * (size_t)p + 1],
                                    dir[3 * (size_t)p + 2], 0.f);
        }
    }
}

// ---------------- main: 4 waves/block, one atom per wave; SGPR indices ----------------
__global__ __launch_bounds__(256) void main_kernel(
    const float* __restrict__ s, const float* __restrict__ v,
    const float* __restrict__ Wij, const unsigned short* __restrict__ v16,
    const unsigned short* __restrict__ t16, const int* __restrict__ offsets_post,
    const int* __restrict__ count, const int2* __restrict__ pjbuf,
    const float4* __restrict__ dbuf,
    float* __restrict__ q_out, float* __restrict__ mu_out, int n_atoms) {
    const int w = threadIdx.x >> 6;
    const int f = threadIdx.x & 63;
    const int i = blockIdx.x * 4 + w;
    if (i >= n_atoms) return;
    const int end = offsets_post[i];
    const int cnt = count[i];
    const int start = end - cnt;

    float accq = 0.f, acc0 = 0.f, acc1 = 0.f, acc2 = 0.f;
    for (int cbase = start; cbase < end; cbase += 64) {
        int m = end - cbase;
        if (m > 64) m = 64;
        int idx = cbase + f;
        int sidx = idx < end ? idx : start;
        int2 pj = pjbuf[sidx];
        float4 dd = dbuf[sidx];
#pragma unroll 2
        for (int k = 0; k < m; ++k) {
            int p = __builtin_amdgcn_readlane(pj.x, k);
            int j = __builtin_amdgcn_readlane(pj.y, k);
            float d0 = __uint_as_float(__builtin_amdgcn_readlane(__float_as_uint(dd.x), k));
            float d1 = __uint_as_float(__builtin_amdgcn_readlane(__float_as_uint(dd.y), k));
            float d2 = __uint_as_float(__builtin_amdgcn_readlane(__float_as_uint(dd.z), k));
            const float* wp = Wij + (size_t)p * TFDIM;
            const unsigned short* tp = t16 + (size_t)j * TFDIM;
            const unsigned short* vp = v16 + (size_t)j * TFDIM;
            float w1 = __builtin_nontemporal_load(wp + f);
            float w2 = __builtin_nontemporal_load(wp + FDIM + f);
            float w3 = __builtin_nontemporal_load(wp + 2 * FDIM + f);
            float t1 = bf2f(tp[f]);
            float t2 = bf2f(tp[FDIM + f]);
            float t3 = bf2f(tp[2 * FDIM + f]);
            float v0 = bf2f(vp[f]);
            float v1 = bf2f(vp[FDIM + f]);
            float v2 = bf2f(vp[2 * FDIM + f]);
            float ds2 = w2 * t2;
            float ds3 = w3 * t3;
            accq = fmaf(w1, t1, accq);
            acc0 = fmaf(ds2, d0, fmaf(ds3, v0, acc0));
            acc1 = fmaf(ds2, d1, fmaf(ds3, v1, acc1));
            acc2 = fmaf(ds2, d2, fmaf(ds3, v2, acc2));
        }
    }

    size_t qb = (size_t)i * FDIM;
    size_t vb = (size_t)i * TFDIM;
    __builtin_nontemporal_store(s[qb + f] + accq, &q_out[qb + f]);
    __builtin_nontemporal_store(v[vb + f] + acc0, &mu_out[vb + f]);
    __builtin_nontemporal_store(v[vb + FDIM + f] + acc1, &mu_out[vb + FDIM + f]);
    __builtin_nontemporal_store(v[vb + 2 * FDIM + f] + acc2, &mu_out[vb + 2 * FDIM + f]);
}

extern "C" void kernel_launch(void* const* d_in, const int* in_sizes, int n_in,
                              void* d_out, int out_size, void* d_ws, size_t ws_size,
                              hipStream_t stream) {
    const float* s   = (const float*)d_in[0];   // [N,1,F]
    const float* v   = (const float*)d_in[1];   // [N,3,F]
    const float* Wij = (const float*)d_in[2];   // [P,3F]
    const float* dir = (const float*)d_in[3];   // [P,3]
    const int*   pl  = (const int*)d_in[4];     // [2,P]
    const float* W1  = (const float*)d_in[5];
    const float* b1  = (const float*)d_in[6];
    const float* W2  = (const float*)d_in[7];
    const float* b2  = (const float*)d_in[8];

    const int n_atoms = in_sizes[0] / FDIM;
    const int n_pairs = in_sizes[3] / 3;
    const int* idx_i = pl;
    const int* idx_j = pl + n_pairs;

    // workspace layout (16B-aligned slices)
    char* ws = (char*)d_ws;
    size_t off = 0;
    auto alloc = [&](size_t bytes) {
        void* ptr = ws + off;
        off = (off + bytes + 15) & ~(size_t)15;
        return ptr;
    };
    unsigned short* t16 = (unsigned short*)alloc((size_t)n_atoms * TFDIM * 2);
    unsigned short* v16 = (unsigned short*)alloc((size_t)n_atoms * TFDIM * 2);
    int* count   = (int*)alloc((size_t)n_atoms * 4);
    int* offsets = (int*)alloc(((size_t)n_atoms + 1) * 4);
    int* bsum    = (int*)alloc(64 * 4);
    int2* pjbuf  = (int2*)alloc((size_t)n_pairs * 8);
    float4* dbuf = (float4*)alloc((size_t)n_pairs * 16);

    float* q_out  = (float*)d_out;                           // [N,1,F]
    float* mu_out = q_out + (size_t)n_atoms * FDIM;          // [N,3,F]

    const int nb = (n_atoms + 1023) / 1024;
    const int nv = n_atoms * TFDIM;

    zero_kernel<<<(n_atoms + 255) / 256, 256, 0, stream>>>(count, n_atoms);
    cvt_kernel<<<((nv >> 2) + 255) / 256, 256, 0, stream>>>(v, v16, nv);
    mlp_kernel<<<(n_atoms + MLP_A - 1) / MLP_A, 64, 0, stream>>>(s, W1, b1, W2, b2, t16, n_atoms);
    hist_kernel<<<1024, 256, 0, stream>>>(idx_i, count, n_pairs);
    scan_local<<<nb, 1024, 0, stream>>>(count, offsets, bsum, n_atoms);
    scan_tops<<<1, 64, 0, stream>>>(bsum, offsets, nb, n_atoms);
    scan_add<<<(n_atoms + 1023) / 1024, 1024, 0, stream>>>(offsets, bsum, n_atoms);
    scatter_kernel<<<1024, 256, 0, stream>>>(idx_i, idx_j, dir, offsets, pjbuf, dbuf, n_pairs);
    main_kernel<<<(n_atoms + 3) / 4, 256, 0, stream>>>(s, v, Wij, v16, t16, offsets, count,
                                                       pjbuf, dbuf, q_out, mu_out, n_atoms);
}